// Round 1
// baseline (446.613 us; speedup 1.0000x reference)
//
#include <hip/hip_runtime.h>
#include <hip/hip_bf16.h>
#include <cstdint>
#include <cstddef>

#define Bn 64
#define Mn 512
#define Dn 2048
#define Kn 32
#define EPSF 1e-12f

typedef __attribute__((ext_vector_type(8))) __bf16 bf16x8;
typedef __attribute__((ext_vector_type(4))) __bf16 bf16x4;
typedef __attribute__((ext_vector_type(4))) float f32x4;

// ---------------- K0: W f32 -> bf16 once --------------------------------------
// Removes per-wave W conversion in K1 (was: every one of 2048 waves re-read and
// re-converted all 256 KB of W) and halves K1's W load-slot usage, freeing
// outstanding-request capacity for x HBM misses (the MLP bottleneck theory).
__global__ __launch_bounds__(256) void k0_wcvt(const float* __restrict__ W,
                                               __bf16* __restrict__ wbf) {
  int i = (blockIdx.x * 256 + threadIdx.x) * 4;
  f32x4 v = *(const f32x4*)(W + i);
  bf16x4 o;
  o[0] = (__bf16)v[0]; o[1] = (__bf16)v[1]; o[2] = (__bf16)v[2]; o[3] = (__bf16)v[3];
  *(bf16x4*)(wbf + i) = o;
}

// ---------------- K1: logits (bf16 MFMA) + fused softmax -> saT bf16 + colsum --
// Occupancy 2x vs previous version: 1024 blocks; waves (g,h) = (row-group,
// D-half). Each wave does 32 K-steps over its 1024-column half; pairs (g,h=0/1)
// combine acc+ssq through LDS. Also stores x as bf16 (xbf) for K3 — identical
// RTNE rounding to the conversion K3 previously did in-register, so K3's math
// is bit-identical while its x bytes halve (134 MB, comfortably LLC-resident).
// C/D layout: lane&15 = k, (lane>>4)*4+r = m (verified mapping).
template <bool XBF>
__global__ __launch_bounds__(256, 4) void k1_logits_softmax(const float* __restrict__ x,
                                                            const __bf16* __restrict__ Wb,
                                                            __bf16* __restrict__ saT,
                                                            float* __restrict__ colsum,
                                                            __bf16* __restrict__ xbf) {
  __shared__ float red[2][64][9];   // pair-combine buffer (stride 9: no bank clash)
  int wv = threadIdx.x >> 6, lane = threadIdx.x & 63;
  int g = wv & 1, h = wv >> 1;
  int mr = lane & 15, q = lane >> 4;
  int blk = blockIdx.x;
  int row0 = blk * 32 + g * 16;     // 16 blocks per b; rows never cross b
  int b = blk >> 4;
  const float* xp = x + (size_t)(row0 + mr) * Dn + h * 1024 + q * 8;
  const __bf16* wp0 = Wb + (size_t)mr * Dn + h * 1024 + q * 8;
  const __bf16* wp1 = Wb + (size_t)(mr + 16) * Dn + h * 1024 + q * 8;
  __bf16* xs = XBF ? (xbf + (size_t)(row0 + mr) * Dn + h * 1024 + q * 8) : nullptr;
  f32x4 acc0 = {0.f, 0.f, 0.f, 0.f};
  f32x4 acc1 = {0.f, 0.f, 0.f, 0.f};
  float ssq = 0.f;
#pragma unroll 2
  for (int s = 0; s < 32; ++s) {
    f32x4 xa = *(const f32x4*)(xp + s * 32);
    f32x4 xb = *(const f32x4*)(xp + s * 32 + 4);
    bf16x8 b0 = *(const bf16x8*)(wp0 + s * 32);
    bf16x8 b1 = *(const bf16x8*)(wp1 + s * 32);
    bf16x8 af;
    af[0] = (__bf16)xa[0]; af[1] = (__bf16)xa[1];
    af[2] = (__bf16)xa[2]; af[3] = (__bf16)xa[3];
    af[4] = (__bf16)xb[0]; af[5] = (__bf16)xb[1];
    af[6] = (__bf16)xb[2]; af[7] = (__bf16)xb[3];
    if constexpr (XBF) *(bf16x8*)(xs + s * 32) = af;   // coalesced 16B/lane store
    ssq = fmaf(xa[0], xa[0], ssq); ssq = fmaf(xa[1], xa[1], ssq);
    ssq = fmaf(xa[2], xa[2], ssq); ssq = fmaf(xa[3], xa[3], ssq);
    ssq = fmaf(xb[0], xb[0], ssq); ssq = fmaf(xb[1], xb[1], ssq);
    ssq = fmaf(xb[2], xb[2], ssq); ssq = fmaf(xb[3], xb[3], ssq);
    acc0 = __builtin_amdgcn_mfma_f32_16x16x32_bf16(af, b0, acc0, 0, 0, 0);
    acc1 = __builtin_amdgcn_mfma_f32_16x16x32_bf16(af, b1, acc1, 0, 0, 0);
  }
  // combine D-half partials across wave pairs (g,h=1) -> (g,h=0)
  if (h == 1) {
#pragma unroll
    for (int r = 0; r < 4; ++r) { red[g][lane][r] = acc0[r]; red[g][lane][4 + r] = acc1[r]; }
    red[g][lane][8] = ssq;
  }
  __syncthreads();
  if (h == 1) return;
#pragma unroll
  for (int r = 0; r < 4; ++r) { acc0[r] += red[g][lane][r]; acc1[r] += red[g][lane][4 + r]; }
  ssq += red[g][lane][8];
  // row sumsq: lane (mr,q) holds quarter of row row0+mr
  ssq += __shfl_xor(ssq, 16);
  ssq += __shfl_xor(ssq, 32);
  float invb = 1.f / fmaxf(sqrtf(ssq), EPSF);
  float cs0 = 0.f, cs1 = 0.f;
  bf16x4 v40, v41;
#pragma unroll
  for (int r = 0; r < 4; ++r) {
    float inv = __shfl(invb, q * 4 + r);        // invnorm of row row0+q*4+r
    float v0 = acc0[r] * inv, v1 = acc1[r] * inv;
    float mx = fmaxf(v0, v1);                   // max over 32 k (16 k-lanes x 2)
    mx = fmaxf(mx, __shfl_xor(mx, 1));
    mx = fmaxf(mx, __shfl_xor(mx, 2));
    mx = fmaxf(mx, __shfl_xor(mx, 4));
    mx = fmaxf(mx, __shfl_xor(mx, 8));
    float e0 = __expf(v0 - mx), e1 = __expf(v1 - mx);
    float sm = e0 + e1;
    sm += __shfl_xor(sm, 1); sm += __shfl_xor(sm, 2);
    sm += __shfl_xor(sm, 4); sm += __shfl_xor(sm, 8);
    float rs = 1.f / sm;
    float sa0 = e0 * rs, sa1 = e1 * rs;
    v40[r] = (__bf16)(sa0 * inv);               // sa' = sa * invnorm
    v41[r] = (__bf16)(sa1 * inv);
    cs0 += sa0; cs1 += sa1;
  }
  int mloc = row0 & 511;
  __bf16* st = saT + ((size_t)(b * Kn + mr)) * Mn + mloc + q * 4;
  *(bf16x4*)st = v40;
  *(bf16x4*)(st + (size_t)16 * Mn) = v41;
  cs0 += __shfl_xor(cs0, 16); cs0 += __shfl_xor(cs0, 32);
  cs1 += __shfl_xor(cs1, 16); cs1 += __shfl_xor(cs1, 32);
  if (lane < 16) {
    atomicAdd(&colsum[b * Kn + mr], cs0);
    atomicAdd(&colsum[b * Kn + mr + 16], cs1);
  }
}

// ---------------- K3: agg = saT @ x via MFMA ----------------------------------
// Occupancy-first redesign: 64-col chunks -> grid 2048 (8 blocks/CU); saT staged
// per-m0-tile (2 KB, double-buffered, padded stride 40 bf16 -> conflict-free
// b128 reads, 16B-aligned) instead of the whole 33 KB panel, so LDS never caps
// occupancy. B-frag x reads are 2B (bf16, XBF path) scalar loads: 16 n-lanes
// cover 32B of each 64B line and the paired warp covers the other half (L1 hit).
template <bool XBF>
__global__ __launch_bounds__(256, 6) void k3_agg(const float* __restrict__ x,
                                                 const __bf16* __restrict__ xbf,
                                                 const __bf16* __restrict__ saT,
                                                 const float* __restrict__ colsum,
                                                 const float* __restrict__ cent,
                                                 float* __restrict__ vlad,
                                                 float* __restrict__ ssq) {
  __shared__ __bf16 tile[2][Kn][40];   // 5.1 KB total
  __shared__ float csl[Kn];
  int b = blockIdx.x >> 5;             // 32 chunks of 64 cols per b
  int chunk = blockIdx.x & 31;
  int t = threadIdx.x;
  int w = t >> 6, lane = t & 63;
  int n = lane & 15, q = lane >> 4;
  int d0 = chunk * 64 + w * 16;        // warp owns 16 d-cols
  int sk = t >> 3, mo = (t & 7) * 4;   // staging: thread -> (k-row, 4 m-cols)
  const __bf16* sg = saT + ((size_t)b * Kn + sk) * Mn + mo;
  if (t < Kn) csl[t] = colsum[b * Kn + t];
  *(bf16x4*)&tile[0][sk][mo] = *(const bf16x4*)sg;   // prologue: tile 0
  const float* xgf = x + (size_t)b * Mn * Dn + d0 + n;
  const __bf16* xgb = XBF ? (xbf + (size_t)b * Mn * Dn + d0 + n) : nullptr;
  f32x4 acc[2] = {};
  for (int it = 0; it < 16; ++it) {
    int m0 = it * 32;
    int cb = it & 1;
    __syncthreads();
    bf16x4 stg = {};
    if (it < 15) stg = *(const bf16x4*)(sg + m0 + 32);   // issue next-tile load early
    bf16x8 bv;
    if constexpr (XBF) {
      const __bf16* xp = xgb + (size_t)(m0 + q * 8) * Dn;
#pragma unroll
      for (int j = 0; j < 8; ++j) bv[j] = xp[(size_t)j * Dn];
    } else {
      const float* xp = xgf + (size_t)(m0 + q * 8) * Dn;
#pragma unroll
      for (int j = 0; j < 8; ++j) bv[j] = (__bf16)xp[(size_t)j * Dn];
    }
    bf16x8 a0 = *(const bf16x8*)&tile[cb][n][q * 8];
    bf16x8 a1 = *(const bf16x8*)&tile[cb][n + 16][q * 8];
    acc[0] = __builtin_amdgcn_mfma_f32_16x16x32_bf16(a0, bv, acc[0], 0, 0, 0);
    acc[1] = __builtin_amdgcn_mfma_f32_16x16x32_bf16(a1, bv, acc[1], 0, 0, 0);
    if (it < 15) *(bf16x4*)&tile[cb ^ 1][sk][mo] = stg;  // write-other-buf: no race
  }
  // epilogue: vlad = agg - colsum*cent (fp32), store + ssq partial atomics
  const float* cg = cent + d0 + n;
#pragma unroll
  for (int kt = 0; kt < 2; ++kt) {
#pragma unroll
    for (int r = 0; r < 4; ++r) {
      int k = kt * 16 + q * 4 + r;
      float vv = acc[kt][r] - csl[k] * cg[(size_t)k * Dn];
      vlad[((size_t)(b * Kn + k)) * Dn + d0 + n] = vv;
      float sq = vv * vv;
      sq += __shfl_xor(sq, 1); sq += __shfl_xor(sq, 2);
      sq += __shfl_xor(sq, 4); sq += __shfl_xor(sq, 8);
      if (n == 0) atomicAdd(&ssq[b * Kn + k], sq);
    }
  }
}

// ---------------- K4: intra-normalize per (b,k) + global L2 normalize, in place
__global__ __launch_bounds__(256) void k4_norm(float* __restrict__ out,
                                               const float* __restrict__ ssq) {
  __shared__ float rk[Kn];
  __shared__ float us[Kn];
  int b = blockIdx.x >> 4;
  int t = threadIdx.x;
  if (t < Kn) {
    float ss = ssq[b * Kn + t];
    float r = 1.f / fmaxf(sqrtf(ss), EPSF);
    rk[t] = r;
    us[t] = ss * r * r;   // = ||u_k||^2 after intra-norm
  }
  __syncthreads();
  float S = 0.f;
#pragma unroll
  for (int k = 0; k < Kn; ++k) S += us[k];
  float s = 1.f / fmaxf(sqrtf(S), EPSF);
  int chunk = blockIdx.x & 15;
  size_t base = (size_t)b * (Kn * Dn) + (size_t)chunk * 4096;
  f32x4* p = (f32x4*)(out + base);
#pragma unroll
  for (int i = 0; i < 4; ++i) {
    int idx = t + 256 * i;                        // float4 index, 0..1023
    int k = (chunk * 4096 + idx * 4) >> 11;       // 2048 floats per k
    f32x4 v = p[idx];
    float sc = rk[k] * s;
    v[0] *= sc; v[1] *= sc; v[2] *= sc; v[3] *= sc;
    p[idx] = v;
  }
}

extern "C" void kernel_launch(void* const* d_in, const int* in_sizes, int n_in,
                              void* d_out, int out_size, void* d_ws, size_t ws_size,
                              hipStream_t stream) {
  const float* x = (const float*)d_in[0];
  const float* W = (const float*)d_in[1];
  const float* cent = (const float*)d_in[2];
  float* out = (float*)d_out;
  char* ws = (char*)d_ws;
  // ws layout: colsum(8K) | ssq(8K) | wbf(128K) | saT(2M) | xbf(128M bf16)
  float* colsum = (float*)ws;
  float* ssqb = (float*)(ws + 8192);
  __bf16* wbf = (__bf16*)(ws + 16384);
  __bf16* saT = (__bf16*)(ws + 16384 + 131072);
  __bf16* xbf = (__bf16*)(ws + 16384 + 131072 + 2097152);
  size_t need_xbf = 16384 + 131072 + 2097152 + (size_t)Bn * Mn * Dn * 2;
  bool use_xbf = ws_size >= need_xbf;
  hipMemsetAsync(ws, 0, 16384, stream);   // zero colsum+ssq (graph-capturable)
  k0_wcvt<<<dim3(64), dim3(256), 0, stream>>>(W, wbf);
  if (use_xbf) {
    k1_logits_softmax<true><<<dim3(1024), dim3(256), 0, stream>>>(x, wbf, saT, colsum, xbf);
    k3_agg<true><<<dim3(2048), dim3(256), 0, stream>>>(x, xbf, saT, colsum, cent, out, ssqb);
  } else {
    k1_logits_softmax<false><<<dim3(1024), dim3(256), 0, stream>>>(x, wbf, saT, colsum, nullptr);
    k3_agg<false><<<dim3(2048), dim3(256), 0, stream>>>(x, nullptr, saT, colsum, cent, out, ssqb);
  }
  k4_norm<<<dim3(1024), dim3(256), 0, stream>>>(out, ssqb);
}